// Round 7
// baseline (141.804 us; speedup 1.0000x reference)
//
#include <hip/hip_runtime.h>
#include <hip/hip_fp16.h>

// PreEncoder float2bit: each input float -> 16 outputs in {-1, +1}.
// w = s<<15 | ((E+15)&31)<<10 | (mant23>>13), s from sign(f+0.001)
// ((f+0.001)==0 -> output 0.0), zero -> 0, NaN -> 0x7E00, ±inf -> 0x7C00/0xFC00.
//
// Ladder: R1 150.5 | R3 nt 157.6 (revert) | R4 grid-stride 143.1 |
// R5 unroll 141.8 | R6 swp+cvt 141.1. Kernel ≈32 us vs fill-kernel 6.5 TB/s
// => mixed read+write HBM stream suspected (turnaround on cold 64B reads).
// This round: TWO-PHASE. Kernel A packs each element to u32 (w | szero<<16)
// in d_ws (8 MB, ~3 us). Kernel B expands packed->±1: reads hit L2/L3
// (just written), making it a near-pure store stream like the fill kernel.

typedef float vfloat4 __attribute__((ext_vector_type(4)));
typedef float vfloat4h __attribute__((ext_vector_type(4)));

__device__ __forceinline__ unsigned decode_w(float f) {
  unsigned u = __float_as_uint(f);
  unsigned a = u & 0x7FFFFFFFu;
  unsigned w;
  if (__builtin_expect(a - 0x38800000u < 0x0F000000u, 1)) {
    // 2^-14 <= |f| < 2^16: truncate mantissa to 10 bits -> exact fp16 convert.
    float tm = __uint_as_float(a & 0xFFFFE000u);
    w = (unsigned)__half_as_ushort(__float2half(tm));
  } else if (a > 0x7F800000u) {
    w = 0x7E00u;                       // NaN (s stays 0: NaN compare false)
  } else if (a == 0x7F800000u) {
    w = 0x7C00u;                       // inf; -inf sign added below
  } else if (a == 0u) {
    w = 0u;                            // zero
  } else {
    int e8 = (int)(a >> 23);
    int E; unsigned mant;
    if (e8 != 0) {
      E = e8 - 127;                    // normal outside fp16 range
      mant = a & 0x7FFFFFu;
    } else {
      int p = 31 - __clz((int)a);      // fp32 subnormal: exact normalize
      E = p - 149;
      mant = (a << (23 - p)) & 0x7FFFFFu;
    }
    w = ((unsigned)((E + 15) & 31) << 10) | (mant >> 13);  // two's-compl &31
  }
  if (f + 0.001f < 0.0f) w |= 0x8000u; // sign quirk, valid for ALL patterns
  return w;
}

// Kernel A: x[n] -> packed[n], packed = w | (szero ? 1<<16 : 0)
__global__ __launch_bounds__(256) void pack_kernel(
    const float* __restrict__ x, unsigned* __restrict__ packed, int n) {
  const int S = gridDim.x * blockDim.x;
  const int tid = blockIdx.x * blockDim.x + threadIdx.x;
  int nv = n >> 2;  // float4 chunks
  const vfloat4* x4 = (const vfloat4*)x;
  for (int i = tid; i < nv; i += S) {
    vfloat4 f = x4[i];
    unsigned p0 = decode_w(f.x) | ((f.x == -0.001f) ? 0x10000u : 0u);
    unsigned p1 = decode_w(f.y) | ((f.y == -0.001f) ? 0x10000u : 0u);
    unsigned p2 = decode_w(f.z) | ((f.z == -0.001f) ? 0x10000u : 0u);
    unsigned p3 = decode_w(f.w) | ((f.w == -0.001f) ? 0x10000u : 0u);
    uint4 o; o.x = p0; o.y = p1; o.z = p2; o.w = p3;
    ((uint4*)packed)[i] = o;
  }
  // tail (n not multiple of 4)
  for (int i = (nv << 2) + tid; i < n; i += S) {
    float f = x[i];
    packed[i] = decode_w(f) | ((f == -0.001f) ? 0x10000u : 0u);
  }
}

// Kernel B: packed -> ±1 float output. Chunk t (float4) = bits of elem t>>2.
__global__ __launch_bounds__(256) void expand_kernel(
    const unsigned* __restrict__ packed, vfloat4* __restrict__ out, int n4) {
  const int S = gridDim.x * blockDim.x;
  int t = blockIdx.x * blockDim.x + threadIdx.x;

  // Main: 4 independent chunks in flight (n4 = 16*S -> 4 clean rounds).
  for (; t + 3 * S < n4; t += 4 * S) {
#pragma unroll
    for (int j = 0; j < 4; ++j) {
      int tj = t + j * S;
      unsigned v = packed[tj >> 2];
      int c = tj & 3;
      unsigned nib = v >> (12 - 4 * c);
      vfloat4 o;
      o.x = __uint_as_float(0xBF800000u ^ ((nib << 28) & 0x80000000u));
      o.y = __uint_as_float(0xBF800000u ^ ((nib << 29) & 0x80000000u));
      o.z = __uint_as_float(0xBF800000u ^ ((nib << 30) & 0x80000000u));
      o.w = __uint_as_float(0xBF800000u ^ (nib << 31));
      if (c == 0 && (v & 0x10000u)) o.x = 0.0f;  // s=0.5 -> output 0.0
      out[tj] = o;
    }
  }
  for (; t < n4; t += S) {
    unsigned v = packed[t >> 2];
    int c = t & 3;
    unsigned nib = v >> (12 - 4 * c);
    vfloat4 o;
    o.x = __uint_as_float(0xBF800000u ^ ((nib << 28) & 0x80000000u));
    o.y = __uint_as_float(0xBF800000u ^ ((nib << 29) & 0x80000000u));
    o.z = __uint_as_float(0xBF800000u ^ ((nib << 30) & 0x80000000u));
    o.w = __uint_as_float(0xBF800000u ^ (nib << 31));
    if (c == 0 && (v & 0x10000u)) o.x = 0.0f;
    out[t] = o;
  }
}

extern "C" void kernel_launch(void* const* d_in, const int* in_sizes, int n_in,
                              void* d_out, int out_size, void* d_ws, size_t ws_size,
                              hipStream_t stream) {
  const float* x = (const float*)d_in[0];
  vfloat4* out = (vfloat4*)d_out;
  unsigned* packed = (unsigned*)d_ws;
  int n = in_sizes[0];
  int n4 = out_size / 4;
  int threads = 256;
  int blocks = 2048;  // 8192 waves = 32/CU on 256 CUs
  pack_kernel<<<1024, threads, 0, stream>>>(x, packed, n);
  expand_kernel<<<blocks, threads, 0, stream>>>(packed, out, n4);
}

// Round 8
// 140.364 us; speedup vs baseline: 1.0103x; 1.0103x over previous
//
#include <hip/hip_runtime.h>
#include <hip/hip_fp16.h>

// PreEncoder float2bit: each input float -> 16 outputs in {-1, +1}.
// w = s<<15 | ((E+15)&31)<<10 | (mant23>>13), with s from sign(f+0.001)
// (f+0.001==0 -> s=0.5 -> output 0.0), zero -> all 0, NaN -> 0x7E00,
// +inf -> 0x7C00, -inf -> 0xFC00.
//
// Ladder: R1 one-shot 150.5 | R3 nt-store 157.6 (reverted) | R4 persistent
// grid-stride 143.1 | R5 unroll x4 141.8 | R6 swp+fp16-cvt decode 141.06 |
// R7 two-phase pack/expand 141.8 (reverted). Four distinct structural
// attacks (store policy, MLP, load pipelining, stream purity) all land
// 141-143: kernel ≈30 us vs 22.6 us pure roofline; residual is L2 drain
// of the harness's 512 MiB poison fill sharing the stream + launch/ramp
// amortization. This is the best measured variant (R6), resubmitted.

typedef float vfloat4 __attribute__((ext_vector_type(4)));

__device__ __forceinline__ unsigned decode_w(float f) {
  unsigned u = __float_as_uint(f);
  unsigned a = u & 0x7FFFFFFFu;
  unsigned w;
  if (__builtin_expect(a - 0x38800000u < 0x0F000000u, 1)) {
    // 2^-14 <= |f| < 2^16: truncate mantissa to 10 bits, convert exactly
    // (value is exactly fp16-representable -> v_cvt_f16_f32 is bit-exact).
    float tm = __uint_as_float(a & 0xFFFFE000u);
    w = (unsigned)__half_as_ushort(__float2half(tm));
  } else if (a > 0x7F800000u) {
    w = 0x7E00u;                       // NaN (s stays 0: NaN compare false)
  } else if (a == 0x7F800000u) {
    w = 0x7C00u;                       // inf; -inf sign added below
  } else if (a == 0u) {
    w = 0u;                            // zero
  } else {
    int e8 = (int)(a >> 23);
    int E; unsigned mant;
    if (e8 != 0) {
      E = e8 - 127;                    // normal outside fp16 range
      mant = a & 0x7FFFFFu;
    } else {
      int p = 31 - __clz((int)a);      // fp32 subnormal: exact normalize
      E = p - 149;
      mant = (a << (23 - p)) & 0x7FFFFFu;
    }
    // low 5 two's-complement bits of (E+15) == floored-div/mod semantics.
    w = ((unsigned)((E + 15) & 31) << 10) | (mant >> 13);
  }
  if (f + 0.001f < 0.0f) w |= 0x8000u; // sign quirk, valid for ALL patterns
  return w;
}

__device__ __forceinline__ vfloat4 extract4(unsigned w, int sh, bool szero) {
  unsigned nib = w >> sh;              // chunk's 4 bits at positions 3..0
  vfloat4 o;
  o.x = __uint_as_float(0xBF800000u ^ ((nib << 28) & 0x80000000u));
  o.y = __uint_as_float(0xBF800000u ^ ((nib << 29) & 0x80000000u));
  o.z = __uint_as_float(0xBF800000u ^ ((nib << 30) & 0x80000000u));
  o.w = __uint_as_float(0xBF800000u ^ (nib << 31));
  if (szero) o.x = 0.0f;               // f == -0.001 exactly -> s = 0.5 -> 0.0
  return o;
}

__global__ __launch_bounds__(256) void preencoder_f2b_kernel(
    const float* __restrict__ x, vfloat4* __restrict__ out, int n4) {
  const int S = gridDim.x * blockDim.x;
  const int tid = blockIdx.x * blockDim.x + threadIdx.x;
  const int c = tid & 3;               // chunk-within-element (S % 4 == 0)
  const int sh = 12 - 4 * c;

  if (n4 == 16 * S) {
    // Specialized: exactly 16 chunks/thread, 4 rounds of 4, pipelined.
    const int S4 = S >> 2;             // element stride between j-slots
    int t = tid;                       // chunk index, round base
    int e = tid >> 2;                  // element index for j=0
    float f[4];
#pragma unroll
    for (int j = 0; j < 4; ++j) f[j] = x[e + j * S4];

#pragma unroll
    for (int r = 0; r < 4; ++r) {
      float g[4] = {0.0f, 0.0f, 0.0f, 0.0f};
      if (r < 3) {
        int en = e + S;                // next round's elements
#pragma unroll
        for (int j = 0; j < 4; ++j) g[j] = x[en + j * S4];
      }
#pragma unroll
      for (int j = 0; j < 4; ++j) {
        bool szero = (c == 0) && (f[j] == -0.001f);
        out[t + j * S] = extract4(decode_w(f[j]), sh, szero);
      }
#pragma unroll
      for (int j = 0; j < 4; ++j) f[j] = g[j];
      e += S;
      t += 4 * S;
    }
  } else {
    // Generic fallback (any n4)
    for (int t = tid; t < n4; t += S) {
      int cc = t & 3;
      bool szero = (cc == 0) && (x[t >> 2] == -0.001f);
      out[t] = extract4(decode_w(x[t >> 2]), 12 - 4 * cc, szero);
    }
  }
}

extern "C" void kernel_launch(void* const* d_in, const int* in_sizes, int n_in,
                              void* d_out, int out_size, void* d_ws, size_t ws_size,
                              hipStream_t stream) {
  const float* x = (const float*)d_in[0];
  vfloat4* out = (vfloat4*)d_out;
  int n4 = out_size / 4;               // one float4 per chunk
  int threads = 256;
  int blocks = 2048;                   // 8192 waves = 32/CU on 256 CUs
  preencoder_f2b_kernel<<<blocks, threads, 0, stream>>>(x, out, n4);
}